// Round 1
// baseline (3250.850 us; speedup 1.0000x reference)
//
#include <hip/hip_runtime.h>
#include <math.h>

#define N_NODES 100000
#define N_NNZ   1000000
#define F_IN    1433
#define F_HID   128
#define F_OUT   64
#define N_POS   20000
#define N_NEG   20000
#define EPS_PN  1e-6f

// ---------------- GEMM: C[M,N] = A[M,K] @ W[K,N] (row-major, fp32) ----------
#define BM 64
#define BN 64
#define BK 16

__global__ __launch_bounds__(256) void gemm_kernel(
    const float* __restrict__ A, const float* __restrict__ W,
    float* __restrict__ C, int M, int K, int N) {
  __shared__ float As[BK][BM];   // transposed A tile
  __shared__ float Bs[BK][BN];
  int tid = threadIdx.x;
  int tx = tid & 15, ty = tid >> 4;
  int row0 = blockIdx.y * BM;
  int col0 = blockIdx.x * BN;
  float acc[4][4] = {};
  for (int k0 = 0; k0 < K; k0 += BK) {
#pragma unroll
    for (int t = 0; t < 4; ++t) {            // A tile: 64 rows x 16 k
      int li = tid + t * 256;
      int r = li >> 4, c = li & 15;
      int gr = row0 + r, gc = k0 + c;
      As[c][r] = (gr < M && gc < K) ? A[(long long)gr * K + gc] : 0.0f;
    }
#pragma unroll
    for (int t = 0; t < 4; ++t) {            // W tile: 16 k x 64 cols
      int li = tid + t * 256;
      int r = li >> 6, c = li & 63;
      int gr = k0 + r, gc = col0 + c;
      Bs[r][c] = (gr < K && gc < N) ? W[(long long)gr * N + gc] : 0.0f;
    }
    __syncthreads();
#pragma unroll
    for (int k = 0; k < BK; ++k) {
      float a[4], b[4];
#pragma unroll
      for (int i = 0; i < 4; ++i) a[i] = As[k][ty * 4 + i];
#pragma unroll
      for (int j = 0; j < 4; ++j) b[j] = Bs[k][tx * 4 + j];
#pragma unroll
      for (int i = 0; i < 4; ++i)
#pragma unroll
        for (int j = 0; j < 4; ++j)
          acc[i][j] += a[i] * b[j];
    }
    __syncthreads();
  }
#pragma unroll
  for (int i = 0; i < 4; ++i) {
    int gr = row0 + ty * 4 + i;
    if (gr >= M) continue;
#pragma unroll
    for (int j = 0; j < 4; ++j) {
      int gc = col0 + tx * 4 + j;
      if (gc < N) C[(long long)gr * N + gc] = acc[i][j];
    }
  }
}

// ---------------- SpMM: y[row] += val * sup[col]  (atomic scatter) ----------
__global__ __launch_bounds__(256) void spmm_kernel(
    const int* __restrict__ row, const int* __restrict__ col,
    const float* __restrict__ val, const float* __restrict__ sup,
    float* __restrict__ y, int nnz, int F) {
  int gid = blockIdx.x * blockDim.x + threadIdx.x;
  int e = gid >> 6;
  int lane = threadIdx.x & 63;
  if (e >= nnz) return;
  int r = row[e], c = col[e];
  float v = val[e];
  const float* sp = sup + (long long)c * F;
  float* yp = y + (long long)r * F;
  for (int f = lane; f < F; f += 64)
    atomicAdd(&yp[f], v * sp[f]);
}

// ---------------- column sums of relu(y + b) --------------------------------
__global__ void colsum_kernel(const float* __restrict__ y,
                              const float* __restrict__ bias,
                              float* __restrict__ csum, int M, int F,
                              int rowsPerBlock) {
  int f = threadIdx.x;                     // blockDim.x == F (64 or 128)
  int r0 = blockIdx.x * rowsPerBlock;
  int r1 = r0 + rowsPerBlock; if (r1 > M) r1 = M;
  float b = bias[f];
  float s = 0.f;
  for (int r = r0; r < r1; ++r) {
    float t = y[(long long)r * F + f] + b;
    s += t > 0.f ? t : 0.f;
  }
  atomicAdd(&csum[f], s);
}

// ---------------- PairNorm: x = (relu(y+b) - colmean) / ||row|| -------------
__global__ __launch_bounds__(256) void pairnorm_kernel(
    const float* __restrict__ y, const float* __restrict__ bias,
    const float* __restrict__ csum, float* __restrict__ x, int M, int F) {
  int gid = blockIdx.x * blockDim.x + threadIdx.x;
  int r = gid >> 6;
  int lane = threadIdx.x & 63;
  if (r >= M) return;
  const float invM = 1.0f / (float)M;
  float z0, z1 = 0.f;
  {
    float t = y[(long long)r * F + lane] + bias[lane];
    t = t > 0.f ? t : 0.f;
    z0 = t - csum[lane] * invM;
  }
  if (F > 64) {
    int f = lane + 64;
    float t = y[(long long)r * F + f] + bias[f];
    t = t > 0.f ? t : 0.f;
    z1 = t - csum[f] * invM;
  }
  float ss = z0 * z0 + z1 * z1;
  for (int o = 32; o > 0; o >>= 1) ss += __shfl_down(ss, o);
  ss = __shfl(ss, 0);
  float rn = 1.0f / sqrtf(EPS_PN + ss);
  x[(long long)r * F + lane] = z0 * rn;
  if (F > 64) x[(long long)r * F + lane + 64] = z1 * rn;
}

// ---------------- decode: sigmoid(dot(x[src], x[dst])) ----------------------
__global__ __launch_bounds__(256) void decode_kernel(
    const int* __restrict__ pos, const int* __restrict__ neg,
    const float* __restrict__ x, float* __restrict__ out,
    int npos, int ntot, int F) {
  int gid = blockIdx.x * blockDim.x + threadIdx.x;
  int e = gid >> 6;
  int lane = threadIdx.x & 63;
  if (e >= ntot) return;
  int src, dst;
  if (e < npos) { src = pos[2 * e];            dst = pos[2 * e + 1]; }
  else          { int q = e - npos; src = neg[2 * q]; dst = neg[2 * q + 1]; }
  float p = x[(long long)src * F + lane] * x[(long long)dst * F + lane];
  for (int o = 32; o > 0; o >>= 1) p += __shfl_down(p, o);
  if (lane == 0) out[e] = 1.0f / (1.0f + expf(-p));
}

extern "C" void kernel_launch(void* const* d_in, const int* in_sizes, int n_in,
                              void* d_out, int out_size, void* d_ws, size_t ws_size,
                              hipStream_t stream) {
  const float* in_feature = (const float*)d_in[0];
  const int*   adj_row    = (const int*)  d_in[1];
  const int*   adj_col    = (const int*)  d_in[2];
  const float* adj_val    = (const float*)d_in[3];
  const int*   pos_ei     = (const int*)  d_in[4];
  const int*   neg_ei     = (const int*)  d_in[5];
  const float* W0 = (const float*)d_in[6];
  const float* b0 = (const float*)d_in[7];
  const float* W1 = (const float*)d_in[8];
  const float* b1 = (const float*)d_in[9];
  const float* W2 = (const float*)d_in[10];
  const float* b2 = (const float*)d_in[11];
  float* out = (float*)d_out;

  char* ws = (char*)d_ws;
  const size_t BUF = (size_t)N_NODES * F_HID * sizeof(float);  // 51.2 MB
  float* sup  = (float*)(ws);
  float* ybuf = (float*)(ws + BUF);
  float* xbuf = (float*)(ws + 2 * BUF);
  float* csum = (float*)(ws + 3 * BUF);

  auto run_layer = [&](const float* xin, int K, const float* W, const float* b,
                       int F) {
    dim3 ggrid((F + BN - 1) / BN, (N_NODES + BM - 1) / BM);
    gemm_kernel<<<ggrid, 256, 0, stream>>>(xin, W, sup, N_NODES, K, F);
    hipMemsetAsync(ybuf, 0, (size_t)N_NODES * F * sizeof(float), stream);
    spmm_kernel<<<(N_NNZ * 64 + 255) / 256, 256, 0, stream>>>(
        adj_row, adj_col, adj_val, sup, ybuf, N_NNZ, F);
    hipMemsetAsync(csum, 0, F * sizeof(float), stream);
    const int rpb = 512;
    colsum_kernel<<<(N_NODES + rpb - 1) / rpb, F, 0, stream>>>(
        ybuf, b, csum, N_NODES, F, rpb);
    pairnorm_kernel<<<(N_NODES * 64 + 255) / 256, 256, 0, stream>>>(
        ybuf, b, csum, xbuf, N_NODES, F);
  };

  run_layer(in_feature, F_IN, W0, b0, F_HID);
  run_layer(xbuf,       F_HID, W1, b1, F_HID);
  run_layer(xbuf,       F_HID, W2, b2, F_OUT);

  decode_kernel<<<((N_POS + N_NEG) * 64 + 255) / 256, 256, 0, stream>>>(
      pos_ei, neg_ei, xbuf, out, N_POS, N_POS + N_NEG, F_OUT);
}

// Round 2
// 2668.451 us; speedup vs baseline: 1.2183x; 1.2183x over previous
//
#include <hip/hip_runtime.h>
#include <math.h>

#define N_NODES 100000
#define N_NNZ   1000000
#define F_IN    1433
#define F_HID   128
#define F_OUT   64
#define N_POS   20000
#define N_NEG   20000
#define EPS_PN  1e-6f

typedef float f32x4  __attribute__((ext_vector_type(4)));
typedef short bf16x8 __attribute__((ext_vector_type(8)));

__device__ inline short f2bf(float f) {
  union { float f; unsigned u; } x; x.f = f;
  unsigned r = x.u + 0x7fff + ((x.u >> 16) & 1);   // round-to-nearest-even
  return (short)(r >> 16);
}

// ---- W cast+transpose: Wt[n][k] (bf16, Kp-padded) from W[k][n] fp32 --------
__global__ __launch_bounds__(256) void wcast_kernel(
    const float* __restrict__ W, short* __restrict__ Wt, int K, int Kp, int N) {
  int idx = blockIdx.x * blockDim.x + threadIdx.x;
  if (idx >= N * Kp) return;
  int n = idx / Kp, k = idx - n * Kp;
  float v = (k < K) ? W[(long long)k * N + n] : 0.0f;
  Wt[idx] = f2bf(v);
}

// ---- MFMA GEMM: C[M,N] = A[M,K] fp32 @ Wt^T (bf16), 4 waves/block ----------
// BMt x BNt tile, BK=32, each wave does a 64x64 sub-tile of 16x16x32 MFMAs.
template<int BMt, int BNt>
__global__ __launch_bounds__(256) void mfma_gemm(
    const float* __restrict__ A, const short* __restrict__ Wt,
    float* __restrict__ C, int M, int K, int Kp, int N) {
  constexpr int LD = 56;                       // row stride in bf16 (112 B)
  __shared__ __align__(16) short As[BMt * LD];
  __shared__ __align__(16) short Ws[BNt * LD];
  constexpr int WN = BNt / 64;                 // waves along n
  constexpr int WM = 4 / WN;                   // waves along m
  int tid = threadIdx.x;
  int lane = tid & 63, w = tid >> 6;
  int wm = w % WM, wn = w / WM;
  int row0 = blockIdx.x * BMt;
  int ml = lane & 15, kgrp = lane >> 4;

  f32x4 acc[4][4] = {};

  for (int k0 = 0; k0 < Kp; k0 += 32) {
    // stage A tile: BMt rows x 32 k, fp32 -> bf16
    for (int e = tid; e < BMt * 32; e += 256) {
      int r = e >> 5, kk = e & 31;
      int gr = row0 + r, gk = k0 + kk;
      float v = (gr < M && gk < K) ? A[(long long)gr * K + gk] : 0.0f;
      As[r * LD + kk] = f2bf(v);
    }
    // stage W tile: BNt rows x 32 k from Wt (16B chunks, already bf16)
    for (int c = tid; c < BNt * 4; c += 256) {
      int n = c >> 2, kk8 = (c & 3) * 8;
      *(bf16x8*)&Ws[n * LD + kk8] =
          *(const bf16x8*)&Wt[(long long)n * Kp + k0 + kk8];
    }
    __syncthreads();

    bf16x8 af[4], bf[4];
#pragma unroll
    for (int i = 0; i < 4; ++i)
      af[i] = *(const bf16x8*)&As[(wm * 64 + i * 16 + ml) * LD + kgrp * 8];
#pragma unroll
    for (int j = 0; j < 4; ++j)
      bf[j] = *(const bf16x8*)&Ws[(wn * 64 + j * 16 + ml) * LD + kgrp * 8];
#pragma unroll
    for (int i = 0; i < 4; ++i)
#pragma unroll
      for (int j = 0; j < 4; ++j)
        acc[i][j] = __builtin_amdgcn_mfma_f32_16x16x32_bf16(
            af[i], bf[j], acc[i][j], 0, 0, 0);
    __syncthreads();
  }

  // epilogue: D mapping col = lane&15, row = (lane>>4)*4 + rr
#pragma unroll
  for (int i = 0; i < 4; ++i)
#pragma unroll
    for (int j = 0; j < 4; ++j)
#pragma unroll
      for (int rr = 0; rr < 4; ++rr) {
        int gr = row0 + wm * 64 + i * 16 + kgrp * 4 + rr;
        int gc = wn * 64 + j * 16 + ml;
        if (gr < M) C[(long long)gr * N + gc] = acc[i][j][rr];
      }
}

// ---------------- SpMM: y[row] += val * sup[col]  (atomic scatter) ----------
__global__ __launch_bounds__(256) void spmm_kernel(
    const int* __restrict__ row, const int* __restrict__ col,
    const float* __restrict__ val, const float* __restrict__ sup,
    float* __restrict__ y, int nnz, int F) {
  int gid = blockIdx.x * blockDim.x + threadIdx.x;
  int e = gid >> 6;
  int lane = threadIdx.x & 63;
  if (e >= nnz) return;
  int r = row[e], c = col[e];
  float v = val[e];
  const float* sp = sup + (long long)c * F;
  float* yp = y + (long long)r * F;
  for (int f = lane; f < F; f += 64)
    atomicAdd(&yp[f], v * sp[f]);
}

// ---------------- column sums of relu(y + b) --------------------------------
__global__ void colsum_kernel(const float* __restrict__ y,
                              const float* __restrict__ bias,
                              float* __restrict__ csum, int M, int F,
                              int rowsPerBlock) {
  int f = threadIdx.x;                     // blockDim.x == F (64 or 128)
  int r0 = blockIdx.x * rowsPerBlock;
  int r1 = r0 + rowsPerBlock; if (r1 > M) r1 = M;
  float b = bias[f];
  float s = 0.f;
  for (int r = r0; r < r1; ++r) {
    float t = y[(long long)r * F + f] + b;
    s += t > 0.f ? t : 0.f;
  }
  atomicAdd(&csum[f], s);
}

// ---------------- PairNorm: x = (relu(y+b) - colmean) / ||row|| -------------
__global__ __launch_bounds__(256) void pairnorm_kernel(
    const float* __restrict__ y, const float* __restrict__ bias,
    const float* __restrict__ csum, float* __restrict__ x, int M, int F) {
  int gid = blockIdx.x * blockDim.x + threadIdx.x;
  int r = gid >> 6;
  int lane = threadIdx.x & 63;
  if (r >= M) return;
  const float invM = 1.0f / (float)M;
  float z0, z1 = 0.f;
  {
    float t = y[(long long)r * F + lane] + bias[lane];
    t = t > 0.f ? t : 0.f;
    z0 = t - csum[lane] * invM;
  }
  if (F > 64) {
    int f = lane + 64;
    float t = y[(long long)r * F + f] + bias[f];
    t = t > 0.f ? t : 0.f;
    z1 = t - csum[f] * invM;
  }
  float ss = z0 * z0 + z1 * z1;
  for (int o = 32; o > 0; o >>= 1) ss += __shfl_down(ss, o);
  ss = __shfl(ss, 0);
  float rn = 1.0f / sqrtf(EPS_PN + ss);
  x[(long long)r * F + lane] = z0 * rn;
  if (F > 64) x[(long long)r * F + lane + 64] = z1 * rn;
}

// ---------------- decode: sigmoid(dot(x[src], x[dst])) ----------------------
__global__ __launch_bounds__(256) void decode_kernel(
    const int* __restrict__ pos, const int* __restrict__ neg,
    const float* __restrict__ x, float* __restrict__ out,
    int npos, int ntot, int F) {
  int gid = blockIdx.x * blockDim.x + threadIdx.x;
  int e = gid >> 6;
  int lane = threadIdx.x & 63;
  if (e >= ntot) return;
  int src, dst;
  if (e < npos) { src = pos[2 * e];            dst = pos[2 * e + 1]; }
  else          { int q = e - npos; src = neg[2 * q]; dst = neg[2 * q + 1]; }
  float p = x[(long long)src * F + lane] * x[(long long)dst * F + lane];
  for (int o = 32; o > 0; o >>= 1) p += __shfl_down(p, o);
  if (lane == 0) out[e] = 1.0f / (1.0f + expf(-p));
}

extern "C" void kernel_launch(void* const* d_in, const int* in_sizes, int n_in,
                              void* d_out, int out_size, void* d_ws, size_t ws_size,
                              hipStream_t stream) {
  const float* in_feature = (const float*)d_in[0];
  const int*   adj_row    = (const int*)  d_in[1];
  const int*   adj_col    = (const int*)  d_in[2];
  const float* adj_val    = (const float*)d_in[3];
  const int*   pos_ei     = (const int*)  d_in[4];
  const int*   neg_ei     = (const int*)  d_in[5];
  const float* W0 = (const float*)d_in[6];
  const float* b0 = (const float*)d_in[7];
  const float* W1 = (const float*)d_in[8];
  const float* b1 = (const float*)d_in[9];
  const float* W2 = (const float*)d_in[10];
  const float* b2 = (const float*)d_in[11];
  float* out = (float*)d_out;

  char* ws = (char*)d_ws;
  const size_t BUF = (size_t)N_NODES * F_HID * sizeof(float);  // 51.2 MB
  float* sup  = (float*)(ws);
  float* ybuf = (float*)(ws + BUF);
  float* xbuf = (float*)(ws + 2 * BUF);
  float* csum = (float*)(ws + 3 * BUF);
  // Wt aliases ybuf: only live between wcast and end of gemm, before ybuf use
  short* Wt   = (short*)ybuf;

  auto run_layer = [&](const float* xin, int K, const float* W, const float* b,
                       int F) {
    int Kp = ((K + 31) / 32) * 32;
    int wcast_n = F * Kp;
    wcast_kernel<<<(wcast_n + 255) / 256, 256, 0, stream>>>(W, Wt, K, Kp, F);
    if (F == 128) {
      mfma_gemm<128, 128><<<(N_NODES + 127) / 128, 256, 0, stream>>>(
          xin, Wt, sup, N_NODES, K, Kp, F);
    } else {
      mfma_gemm<256, 64><<<(N_NODES + 255) / 256, 256, 0, stream>>>(
          xin, Wt, sup, N_NODES, K, Kp, F);
    }
    hipMemsetAsync(ybuf, 0, (size_t)N_NODES * F * sizeof(float), stream);
    spmm_kernel<<<(N_NNZ * 64 + 255) / 256, 256, 0, stream>>>(
        adj_row, adj_col, adj_val, sup, ybuf, N_NNZ, F);
    hipMemsetAsync(csum, 0, F * sizeof(float), stream);
    const int rpb = 512;
    colsum_kernel<<<(N_NODES + rpb - 1) / rpb, F, 0, stream>>>(
        ybuf, b, csum, N_NODES, F, rpb);
    pairnorm_kernel<<<(N_NODES * 64 + 255) / 256, 256, 0, stream>>>(
        ybuf, b, csum, xbuf, N_NODES, F);
  };

  run_layer(in_feature, F_IN, W0, b0, F_HID);
  run_layer(xbuf,       F_HID, W1, b1, F_HID);
  run_layer(xbuf,       F_HID, W2, b2, F_OUT);

  decode_kernel<<<((N_POS + N_NEG) * 64 + 255) / 256, 256, 0, stream>>>(
      pos_ei, neg_ei, xbuf, out, N_POS, N_POS + N_NEG, F_OUT);
}

// Round 3
// 1784.406 us; speedup vs baseline: 1.8218x; 1.4954x over previous
//
#include <hip/hip_runtime.h>
#include <math.h>

#define N_NODES 100000
#define N_NNZ   1000000
#define F_IN    1433
#define F_HID   128
#define F_OUT   64
#define N_POS   20000
#define N_NEG   20000
#define EPS_PN  1e-6f

typedef float f32x4   __attribute__((ext_vector_type(4)));
typedef float f32x4u  __attribute__((ext_vector_type(4), aligned(4)));
typedef short bf16x8  __attribute__((ext_vector_type(8)));
typedef short bf16x4  __attribute__((ext_vector_type(4)));

__device__ inline short f2bf(float f) {
  union { float f; unsigned u; } x; x.f = f;
  unsigned r = x.u + 0x7fff + ((x.u >> 16) & 1);   // round-to-nearest-even
  return (short)(r >> 16);
}

// ---- W cast+transpose: Wt[n][k] (bf16, Kp-padded) from W[k][n] fp32 --------
__global__ __launch_bounds__(256) void wcast_kernel(
    const float* __restrict__ W, short* __restrict__ Wt, int K, int Kp, int N) {
  int idx = blockIdx.x * blockDim.x + threadIdx.x;
  if (idx >= N * Kp) return;
  int n = idx / Kp, k = idx - n * Kp;
  float v = (k < K) ? W[(long long)k * N + n] : 0.0f;
  Wt[idx] = f2bf(v);
}

// ---- MFMA GEMM with register-prefetch double buffering ---------------------
// C[M,N] = A[M,K] fp32 @ Wt^T (bf16). BMt x BNt tile, BK=32, 4 waves/block.
template<int BMt, int BNt>
__global__ __launch_bounds__(256) void mfma_gemm(
    const float* __restrict__ A, const short* __restrict__ Wt,
    float* __restrict__ C, int M, int K, int Kp, int N) {
  constexpr int LD = 40;                       // row stride in shorts (80 B)
  constexpr int APF = BMt / 32;                // float4 loads of A per thread
  constexpr int WPF = BNt / 64;                // bf16x8 loads of W per thread
  __shared__ __align__(16) short As[BMt * LD];
  __shared__ __align__(16) short Ws[BNt * LD];
  constexpr int WN = BNt / 64;
  constexpr int WM = 4 / WN;
  int tid = threadIdx.x;
  int lane = tid & 63, w = tid >> 6;
  int wm = w % WM, wn = w / WM;
  int row0 = blockIdx.x * BMt;
  int ml = lane & 15, kgrp = lane >> 4;

  f32x4 acc[4][4] = {};
  f32x4 pa[APF];
  bf16x8 pw[WPF];

  auto load_a = [&](int k0, f32x4* dst) {
#pragma unroll
    for (int q = 0; q < APF; ++q) {
      int idx = tid + q * 256;
      int r = idx >> 3, k4 = (idx & 7) * 4;
      int gr = row0 + r, gk = k0 + k4;
      f32x4 v = {0.f, 0.f, 0.f, 0.f};
      if (gr < M) {
        if (gk + 3 < K) v = *(const f32x4u*)&A[(long long)gr * K + gk];
        else {
#pragma unroll
          for (int i = 0; i < 4; ++i)
            if (gk + i < K) v[i] = A[(long long)gr * K + gk + i];
        }
      }
      dst[q] = v;
    }
  };
  auto load_w = [&](int k0, bf16x8* dst) {
#pragma unroll
    for (int q = 0; q < WPF; ++q) {
      int idx = tid + q * 256;
      int n = idx >> 2, kk8 = (idx & 3) * 8;
      dst[q] = *(const bf16x8*)&Wt[(long long)n * Kp + k0 + kk8];
    }
  };

  load_a(0, pa);
  load_w(0, pw);

  for (int k0 = 0; k0 < Kp; k0 += 32) {
    // store staged regs -> LDS
#pragma unroll
    for (int q = 0; q < APF; ++q) {
      int idx = tid + q * 256;
      int r = idx >> 3, k4 = (idx & 7) * 4;
      bf16x4 b; 
#pragma unroll
      for (int i = 0; i < 4; ++i) b[i] = f2bf(pa[q][i]);
      *(bf16x4*)&As[r * LD + k4] = b;
    }
#pragma unroll
    for (int q = 0; q < WPF; ++q) {
      int idx = tid + q * 256;
      int n = idx >> 2, kk8 = (idx & 3) * 8;
      *(bf16x8*)&Ws[n * LD + kk8] = pw[q];
    }
    __syncthreads();

    // prefetch next tile while MFMAs run
    if (k0 + 32 < Kp) {
      load_a(k0 + 32, pa);
      load_w(k0 + 32, pw);
    }

    bf16x8 af[4], bf[4];
#pragma unroll
    for (int i = 0; i < 4; ++i)
      af[i] = *(const bf16x8*)&As[(wm * 64 + i * 16 + ml) * LD + kgrp * 8];
#pragma unroll
    for (int j = 0; j < 4; ++j)
      bf[j] = *(const bf16x8*)&Ws[(wn * 64 + j * 16 + ml) * LD + kgrp * 8];
#pragma unroll
    for (int i = 0; i < 4; ++i)
#pragma unroll
      for (int j = 0; j < 4; ++j)
        acc[i][j] = __builtin_amdgcn_mfma_f32_16x16x32_bf16(
            af[i], bf[j], acc[i][j], 0, 0, 0);
    __syncthreads();
  }

  // epilogue: D mapping col = lane&15, row = (lane>>4)*4 + rr
#pragma unroll
  for (int i = 0; i < 4; ++i)
#pragma unroll
    for (int j = 0; j < 4; ++j)
#pragma unroll
      for (int rr = 0; rr < 4; ++rr) {
        int gr = row0 + wm * 64 + i * 16 + kgrp * 4 + rr;
        int gc = wn * 64 + j * 16 + ml;
        if (gr < M) C[(long long)gr * N + gc] = acc[i][j][rr];
      }
}

// ---------------- CSR build -------------------------------------------------
__global__ __launch_bounds__(256) void hist_kernel(
    const int* __restrict__ row, int* __restrict__ cnt, int nnz) {
  int i = blockIdx.x * blockDim.x + threadIdx.x;
  if (i < nnz) atomicAdd(&cnt[row[i]], 1);
}

// single-block exclusive scan of cnt[0..n) -> row_ptr & cursor; row_ptr[n]=nnz
__global__ __launch_bounds__(1024) void scan_kernel(
    const int* __restrict__ cnt, int* __restrict__ row_ptr,
    int* __restrict__ cursor, int n, int nnz) {
  __shared__ int part[1024];
  int t = threadIdx.x;
  int chunk = (n + 1023) >> 10;
  int s0 = t * chunk, s1 = s0 + chunk; if (s1 > n) s1 = n; if (s0 > n) s0 = n;
  int s = 0;
  for (int i = s0; i < s1; ++i) s += cnt[i];
  part[t] = s;
  __syncthreads();
  for (int off = 1; off < 1024; off <<= 1) {
    int v = (t >= off) ? part[t - off] : 0;
    __syncthreads();
    part[t] += v;
    __syncthreads();
  }
  int run = part[t] - s;                      // exclusive prefix
  for (int i = s0; i < s1; ++i) {
    row_ptr[i] = run; cursor[i] = run;
    run += cnt[i];
  }
  if (t == 0) row_ptr[n] = nnz;
}

__global__ __launch_bounds__(256) void scatter_kernel(
    const int* __restrict__ row, const int* __restrict__ col,
    const float* __restrict__ val, int* __restrict__ cursor,
    int* __restrict__ scol, float* __restrict__ sval, int nnz) {
  int i = blockIdx.x * blockDim.x + threadIdx.x;
  if (i >= nnz) return;
  int p = atomicAdd(&cursor[row[i]], 1);
  scol[p] = col[i];
  sval[p] = val[i];
}

// ---- CSR SpMM fused with bias+relu: z[r] = relu(sum val*sup[col] + b) ------
__global__ __launch_bounds__(256) void spmm_csr_kernel(
    const int* __restrict__ rp, const int* __restrict__ scol,
    const float* __restrict__ sval, const float* __restrict__ sup,
    const float* __restrict__ bias, float* __restrict__ z, int M, int F) {
  int gid = blockIdx.x * blockDim.x + threadIdx.x;
  int r = gid >> 6;
  int lane = threadIdx.x & 63;
  if (r >= M) return;
  int j0 = rp[r], j1 = rp[r + 1];
  float a0 = 0.f, a1 = 0.f;
  for (int j = j0; j < j1; ++j) {
    int c = scol[j];
    float v = sval[j];
    const float* sp = sup + (long long)c * F;
    a0 += v * sp[lane];
    if (F > 64) a1 += v * sp[lane + 64];
  }
  float z0 = a0 + bias[lane]; z0 = z0 > 0.f ? z0 : 0.f;
  z[(long long)r * F + lane] = z0;
  if (F > 64) {
    float z1 = a1 + bias[lane + 64]; z1 = z1 > 0.f ? z1 : 0.f;
    z[(long long)r * F + lane + 64] = z1;
  }
}

// ---------------- column sums of z ------------------------------------------
__global__ void colsum_kernel(const float* __restrict__ z,
                              float* __restrict__ csum, int M, int F,
                              int rowsPerBlock) {
  int f = threadIdx.x;                     // blockDim.x == F
  int r0 = blockIdx.x * rowsPerBlock;
  int r1 = r0 + rowsPerBlock; if (r1 > M) r1 = M;
  float s = 0.f;
  for (int r = r0; r < r1; ++r) s += z[(long long)r * F + f];
  atomicAdd(&csum[f], s);
}

// ---------------- PairNorm in place: x = (z - colmean) / ||row|| ------------
__global__ __launch_bounds__(256) void pairnorm_kernel(
    float* __restrict__ x, const float* __restrict__ csum, int M, int F) {
  int gid = blockIdx.x * blockDim.x + threadIdx.x;
  int r = gid >> 6;
  int lane = threadIdx.x & 63;
  if (r >= M) return;
  const float invM = 1.0f / (float)M;
  float z0 = x[(long long)r * F + lane] - csum[lane] * invM;
  float z1 = 0.f;
  if (F > 64) z1 = x[(long long)r * F + lane + 64] - csum[lane + 64] * invM;
  float ss = z0 * z0 + z1 * z1;
  for (int o = 32; o > 0; o >>= 1) ss += __shfl_down(ss, o);
  ss = __shfl(ss, 0);
  float rn = 1.0f / sqrtf(EPS_PN + ss);
  x[(long long)r * F + lane] = z0 * rn;
  if (F > 64) x[(long long)r * F + lane + 64] = z1 * rn;
}

// ---------------- decode: sigmoid(dot(x[src], x[dst])) ----------------------
__global__ __launch_bounds__(256) void decode_kernel(
    const int* __restrict__ pos, const int* __restrict__ neg,
    const float* __restrict__ x, float* __restrict__ out,
    int npos, int ntot, int F) {
  int gid = blockIdx.x * blockDim.x + threadIdx.x;
  int e = gid >> 6;
  int lane = threadIdx.x & 63;
  if (e >= ntot) return;
  int src, dst;
  if (e < npos) { src = pos[2 * e];            dst = pos[2 * e + 1]; }
  else          { int q = e - npos; src = neg[2 * q]; dst = neg[2 * q + 1]; }
  float p = x[(long long)src * F + lane] * x[(long long)dst * F + lane];
  for (int o = 32; o > 0; o >>= 1) p += __shfl_down(p, o);
  if (lane == 0) out[e] = 1.0f / (1.0f + expf(-p));
}

extern "C" void kernel_launch(void* const* d_in, const int* in_sizes, int n_in,
                              void* d_out, int out_size, void* d_ws, size_t ws_size,
                              hipStream_t stream) {
  const float* in_feature = (const float*)d_in[0];
  const int*   adj_row    = (const int*)  d_in[1];
  const int*   adj_col    = (const int*)  d_in[2];
  const float* adj_val    = (const float*)d_in[3];
  const int*   pos_ei     = (const int*)  d_in[4];
  const int*   neg_ei     = (const int*)  d_in[5];
  const float* W0 = (const float*)d_in[6];
  const float* b0 = (const float*)d_in[7];
  const float* W1 = (const float*)d_in[8];
  const float* b1 = (const float*)d_in[9];
  const float* W2 = (const float*)d_in[10];
  const float* b2 = (const float*)d_in[11];
  float* out = (float*)d_out;

  char* ws = (char*)d_ws;
  const size_t BUF = (size_t)N_NODES * F_HID * sizeof(float);  // 51.2 MB
  float* sup     = (float*)(ws);
  float* xbuf    = (float*)(ws + BUF);
  short* Wt      = (short*)(ws + 2 * BUF);                     // 512 KB max
  float* csum    = (float*)(ws + 2 * BUF + (1 << 19));
  int*   cnt     = (int*)  (ws + 2 * BUF + (1 << 19) + 4096);
  int*   row_ptr = (int*)  (ws + 2 * BUF + (1 << 19) + 4096 + (1 << 19));
  int*   cursor  = (int*)  (ws + 2 * BUF + (1 << 19) + 4096 + 2 * (1 << 19));
  int*   scol    = (int*)  (ws + 2 * BUF + (1 << 19) + 4096 + 3 * (1 << 19));
  float* sval    = (float*)(ws + 2 * BUF + (1 << 19) + 4096 + 3 * (1 << 19) +
                            (size_t)N_NNZ * 4);

  // ---- build CSR (once; reused by all 3 layers) ----
  hipMemsetAsync(cnt, 0, (size_t)N_NODES * sizeof(int), stream);
  hist_kernel<<<(N_NNZ + 255) / 256, 256, 0, stream>>>(adj_row, cnt, N_NNZ);
  scan_kernel<<<1, 1024, 0, stream>>>(cnt, row_ptr, cursor, N_NODES, N_NNZ);
  scatter_kernel<<<(N_NNZ + 255) / 256, 256, 0, stream>>>(
      adj_row, adj_col, adj_val, cursor, scol, sval, N_NNZ);

  auto run_layer = [&](const float* xin, int K, const float* W, const float* b,
                       int F) {
    int Kp = ((K + 31) / 32) * 32;
    wcast_kernel<<<(F * Kp + 255) / 256, 256, 0, stream>>>(W, Wt, K, Kp, F);
    if (F == 128) {
      mfma_gemm<128, 128><<<(N_NODES + 127) / 128, 256, 0, stream>>>(
          xin, Wt, sup, N_NODES, K, Kp, F);
    } else {
      mfma_gemm<256, 64><<<(N_NODES + 255) / 256, 256, 0, stream>>>(
          xin, Wt, sup, N_NODES, K, Kp, F);
    }
    spmm_csr_kernel<<<(N_NODES * 64 + 255) / 256, 256, 0, stream>>>(
        row_ptr, scol, sval, sup, b, xbuf, N_NODES, F);
    hipMemsetAsync(csum, 0, F * sizeof(float), stream);
    colsum_kernel<<<(N_NODES + 127) / 128, F, 0, stream>>>(
        xbuf, csum, N_NODES, F, 128);
    pairnorm_kernel<<<(N_NODES * 64 + 255) / 256, 256, 0, stream>>>(
        xbuf, csum, N_NODES, F);
  };

  run_layer(in_feature, F_IN, W0, b0, F_HID);
  run_layer(xbuf,       F_HID, W1, b1, F_HID);
  run_layer(xbuf,       F_HID, W2, b2, F_OUT);

  decode_kernel<<<((N_POS + N_NEG) * 64 + 255) / 256, 256, 0, stream>>>(
      pos_ei, neg_ei, xbuf, out, N_POS, N_POS + N_NEG, F_OUT);
}

// Round 4
// 1743.663 us; speedup vs baseline: 1.8644x; 1.0234x over previous
//
#include <hip/hip_runtime.h>
#include <math.h>

#define N_NODES 100000
#define N_NNZ   1000000
#define F_IN    1433
#define F_HID   128
#define F_OUT   64
#define N_POS   20000
#define N_NEG   20000
#define EPS_PN  1e-6f

typedef float f32x2   __attribute__((ext_vector_type(2)));
typedef float f32x4   __attribute__((ext_vector_type(4)));
typedef float f32x4u  __attribute__((ext_vector_type(4), aligned(4)));
typedef short bf16x8  __attribute__((ext_vector_type(8)));
typedef short bf16x4  __attribute__((ext_vector_type(4)));

__device__ inline short f2bf(float f) {
  union { float f; unsigned u; } x; x.f = f;
  unsigned r = x.u + 0x7fff + ((x.u >> 16) & 1);   // round-to-nearest-even
  return (short)(r >> 16);
}

// ---- W cast+transpose: Wt[n][k] (bf16, Kp-padded) from W[k][n] fp32 --------
__global__ __launch_bounds__(256) void wcast_kernel(
    const float* __restrict__ W, short* __restrict__ Wt, int K, int Kp, int N) {
  int idx = blockIdx.x * blockDim.x + threadIdx.x;
  if (idx >= N * Kp) return;
  int n = idx / Kp, k = idx - n * Kp;
  float v = (k < K) ? W[(long long)k * N + n] : 0.0f;
  Wt[idx] = f2bf(v);
}

// ---- MFMA GEMM, register-prefetch double buffering -------------------------
// C[M,N] = A[M,K] fp32 @ Wt^T (bf16). 4 waves/block arranged WM x WN;
// per-wave tile (MI*16) x (NJ*16).
template<int BMt, int BNt, int WM, int WN>
__global__ __launch_bounds__(256) void mfma_gemm(
    const float* __restrict__ A, const short* __restrict__ Wt,
    float* __restrict__ C, int M, int K, int Kp, int N) {
  constexpr int LD  = 40;                      // LDS row stride in shorts
  constexpr int MI  = BMt / (WM * 16);
  constexpr int NJ  = BNt / (WN * 16);
  constexpr int APF = (BMt * 32) / (256 * 4);  // f32x4 loads of A per thread
  constexpr int WPF = (BNt * 32) / (256 * 8);  // bf16x8 loads of W per thread
  __shared__ __align__(16) short As[BMt * LD];
  __shared__ __align__(16) short Ws[BNt * LD];
  int tid = threadIdx.x;
  int lane = tid & 63, w = tid >> 6;
  int wm = w % WM, wn = w / WM;
  int row0 = blockIdx.x * BMt;
  int ml = lane & 15, kgrp = lane >> 4;

  f32x4 acc[MI][NJ] = {};
  f32x4 pa[APF];
  bf16x8 pw[WPF];

  auto load_a = [&](int k0, f32x4* dst) {
#pragma unroll
    for (int q = 0; q < APF; ++q) {
      int idx = tid + q * 256;
      int r = idx >> 3, k4 = (idx & 7) * 4;
      int gr = row0 + r, gk = k0 + k4;
      f32x4 v = {0.f, 0.f, 0.f, 0.f};
      if (gr < M) {
        if (gk + 3 < K) v = *(const f32x4u*)&A[(long long)gr * K + gk];
        else {
#pragma unroll
          for (int i = 0; i < 4; ++i)
            if (gk + i < K) v[i] = A[(long long)gr * K + gk + i];
        }
      }
      dst[q] = v;
    }
  };
  auto load_w = [&](int k0, bf16x8* dst) {
#pragma unroll
    for (int q = 0; q < WPF; ++q) {
      int idx = tid + q * 256;
      int n = idx >> 2, kk8 = (idx & 3) * 8;
      dst[q] = *(const bf16x8*)&Wt[(long long)n * Kp + k0 + kk8];
    }
  };

  load_a(0, pa);
  load_w(0, pw);

  for (int k0 = 0; k0 < Kp; k0 += 32) {
#pragma unroll
    for (int q = 0; q < APF; ++q) {
      int idx = tid + q * 256;
      int r = idx >> 3, k4 = (idx & 7) * 4;
      bf16x4 b;
#pragma unroll
      for (int i = 0; i < 4; ++i) b[i] = f2bf(pa[q][i]);
      *(bf16x4*)&As[r * LD + k4] = b;
    }
#pragma unroll
    for (int q = 0; q < WPF; ++q) {
      int idx = tid + q * 256;
      int n = idx >> 2, kk8 = (idx & 3) * 8;
      *(bf16x8*)&Ws[n * LD + kk8] = pw[q];
    }
    __syncthreads();

    if (k0 + 32 < Kp) {           // prefetch next tile during MFMAs
      load_a(k0 + 32, pa);
      load_w(k0 + 32, pw);
    }

    bf16x8 af[MI], bfr[NJ];
#pragma unroll
    for (int i = 0; i < MI; ++i)
      af[i] = *(const bf16x8*)&As[(wm * MI * 16 + i * 16 + ml) * LD + kgrp * 8];
#pragma unroll
    for (int j = 0; j < NJ; ++j)
      bfr[j] = *(const bf16x8*)&Ws[(wn * NJ * 16 + j * 16 + ml) * LD + kgrp * 8];
#pragma unroll
    for (int i = 0; i < MI; ++i)
#pragma unroll
      for (int j = 0; j < NJ; ++j)
        acc[i][j] = __builtin_amdgcn_mfma_f32_16x16x32_bf16(
            af[i], bfr[j], acc[i][j], 0, 0, 0);
    __syncthreads();
  }

  // epilogue: D mapping col = lane&15, row = (lane>>4)*4 + rr
#pragma unroll
  for (int i = 0; i < MI; ++i)
#pragma unroll
    for (int j = 0; j < NJ; ++j)
#pragma unroll
      for (int rr = 0; rr < 4; ++rr) {
        int gr = row0 + wm * MI * 16 + i * 16 + kgrp * 4 + rr;
        int gc = wn * NJ * 16 + j * 16 + ml;
        if (gr < M) C[(long long)gr * N + gc] = acc[i][j][rr];
      }
}

// ---------------- CSR build -------------------------------------------------
__global__ __launch_bounds__(256) void hist_kernel(
    const int* __restrict__ row, int* __restrict__ cnt, int nnz) {
  int i = blockIdx.x * blockDim.x + threadIdx.x;
  if (i < nnz) atomicAdd(&cnt[row[i]], 1);
}

__global__ __launch_bounds__(1024) void scan_kernel(
    const int* __restrict__ cnt, int* __restrict__ row_ptr,
    int* __restrict__ cursor, int n, int nnz) {
  __shared__ int part[1024];
  int t = threadIdx.x;
  int chunk = (n + 1023) >> 10;
  int s0 = t * chunk, s1 = s0 + chunk; if (s1 > n) s1 = n; if (s0 > n) s0 = n;
  int s = 0;
  for (int i = s0; i < s1; ++i) s += cnt[i];
  part[t] = s;
  __syncthreads();
  for (int off = 1; off < 1024; off <<= 1) {
    int v = (t >= off) ? part[t - off] : 0;
    __syncthreads();
    part[t] += v;
    __syncthreads();
  }
  int run = part[t] - s;                      // exclusive prefix
  for (int i = s0; i < s1; ++i) {
    row_ptr[i] = run; cursor[i] = run;
    run += cnt[i];
  }
  if (t == 0) row_ptr[n] = nnz;
}

__global__ __launch_bounds__(256) void scatter_kernel(
    const int* __restrict__ row, const int* __restrict__ col,
    const float* __restrict__ val, int* __restrict__ cursor,
    int* __restrict__ scol, float* __restrict__ sval, int nnz) {
  int i = blockIdx.x * blockDim.x + threadIdx.x;
  if (i >= nnz) return;
  int p = atomicAdd(&cursor[row[i]], 1);
  scol[p] = col[i];
  sval[p] = val[i];
}

// ---- CSR SpMM fused bias+relu, F=128: lane owns feats {2l, 2l+1} -----------
__global__ __launch_bounds__(256) void spmm_csr128_kernel(
    const int* __restrict__ rp, const int* __restrict__ scol,
    const float* __restrict__ sval, const float* __restrict__ sup,
    const float* __restrict__ bias, float* __restrict__ z, int M) {
  int gid = blockIdx.x * blockDim.x + threadIdx.x;
  int r = gid >> 6;
  int lane = threadIdx.x & 63;
  if (r >= M) return;
  int j0 = rp[r], j1 = rp[r + 1];
  f32x2 a = {0.f, 0.f};
  for (int j = j0; j < j1; ++j) {
    int c = scol[j];
    float v = sval[j];
    f32x2 s = *(const f32x2*)&sup[(long long)c * 128 + 2 * lane];
    a.x += v * s.x;
    a.y += v * s.y;
  }
  f32x2 b = *(const f32x2*)&bias[2 * lane];
  f32x2 zz;
  zz.x = a.x + b.x; zz.x = zz.x > 0.f ? zz.x : 0.f;
  zz.y = a.y + b.y; zz.y = zz.y > 0.f ? zz.y : 0.f;
  *(f32x2*)&z[(long long)r * 128 + 2 * lane] = zz;
}

// ---- CSR SpMM fused bias+relu, F=64 ----------------------------------------
__global__ __launch_bounds__(256) void spmm_csr64_kernel(
    const int* __restrict__ rp, const int* __restrict__ scol,
    const float* __restrict__ sval, const float* __restrict__ sup,
    const float* __restrict__ bias, float* __restrict__ z, int M) {
  int gid = blockIdx.x * blockDim.x + threadIdx.x;
  int r = gid >> 6;
  int lane = threadIdx.x & 63;
  if (r >= M) return;
  int j0 = rp[r], j1 = rp[r + 1];
  float a = 0.f;
  for (int j = j0; j < j1; ++j) {
    int c = scol[j];
    float v = sval[j];
    a += v * sup[(long long)c * 64 + lane];
  }
  float zz = a + bias[lane];
  zz = zz > 0.f ? zz : 0.f;
  z[(long long)r * 64 + lane] = zz;
}

// ---------------- column sums of z ------------------------------------------
__global__ void colsum_kernel(const float* __restrict__ z,
                              float* __restrict__ csum, int M, int F,
                              int rowsPerBlock) {
  int f = threadIdx.x;                     // blockDim.x == F
  int r0 = blockIdx.x * rowsPerBlock;
  int r1 = r0 + rowsPerBlock; if (r1 > M) r1 = M;
  float s = 0.f;
  for (int r = r0; r < r1; ++r) s += z[(long long)r * F + f];
  atomicAdd(&csum[f], s);
}

// ---------------- PairNorm in place: x = (z - colmean) / ||row|| ------------
__global__ __launch_bounds__(256) void pairnorm_kernel(
    float* __restrict__ x, const float* __restrict__ csum, int M, int F) {
  int gid = blockIdx.x * blockDim.x + threadIdx.x;
  int r = gid >> 6;
  int lane = threadIdx.x & 63;
  if (r >= M) return;
  const float invM = 1.0f / (float)M;
  float z0 = x[(long long)r * F + lane] - csum[lane] * invM;
  float z1 = 0.f;
  if (F > 64) z1 = x[(long long)r * F + lane + 64] - csum[lane + 64] * invM;
  float ss = z0 * z0 + z1 * z1;
  for (int o = 32; o > 0; o >>= 1) ss += __shfl_down(ss, o);
  ss = __shfl(ss, 0);
  float rn = 1.0f / sqrtf(EPS_PN + ss);
  x[(long long)r * F + lane] = z0 * rn;
  if (F > 64) x[(long long)r * F + lane + 64] = z1 * rn;
}

// ---------------- decode: sigmoid(dot(x[src], x[dst])) ----------------------
__global__ __launch_bounds__(256) void decode_kernel(
    const int* __restrict__ pos, const int* __restrict__ neg,
    const float* __restrict__ x, float* __restrict__ out,
    int npos, int ntot, int F) {
  int gid = blockIdx.x * blockDim.x + threadIdx.x;
  int e = gid >> 6;
  int lane = threadIdx.x & 63;
  if (e >= ntot) return;
  int src, dst;
  if (e < npos) { src = pos[2 * e];            dst = pos[2 * e + 1]; }
  else          { int q = e - npos; src = neg[2 * q]; dst = neg[2 * q + 1]; }
  float p = x[(long long)src * F + lane] * x[(long long)dst * F + lane];
  for (int o = 32; o > 0; o >>= 1) p += __shfl_down(p, o);
  if (lane == 0) out[e] = 1.0f / (1.0f + expf(-p));
}

extern "C" void kernel_launch(void* const* d_in, const int* in_sizes, int n_in,
                              void* d_out, int out_size, void* d_ws, size_t ws_size,
                              hipStream_t stream) {
  const float* in_feature = (const float*)d_in[0];
  const int*   adj_row    = (const int*)  d_in[1];
  const int*   adj_col    = (const int*)  d_in[2];
  const float* adj_val    = (const float*)d_in[3];
  const int*   pos_ei     = (const int*)  d_in[4];
  const int*   neg_ei     = (const int*)  d_in[5];
  const float* W0 = (const float*)d_in[6];
  const float* b0 = (const float*)d_in[7];
  const float* W1 = (const float*)d_in[8];
  const float* b1 = (const float*)d_in[9];
  const float* W2 = (const float*)d_in[10];
  const float* b2 = (const float*)d_in[11];
  float* out = (float*)d_out;

  char* ws = (char*)d_ws;
  const size_t BUF = (size_t)N_NODES * F_HID * sizeof(float);  // 51.2 MB
  float* sup     = (float*)(ws);
  float* xbuf    = (float*)(ws + BUF);
  short* Wt      = (short*)(ws + 2 * BUF);                     // 512 KB max
  float* csum    = (float*)(ws + 2 * BUF + (1 << 19));
  int*   cnt     = (int*)  (ws + 2 * BUF + (1 << 19) + 4096);
  int*   row_ptr = (int*)  (ws + 2 * BUF + (1 << 19) + 4096 + (1 << 19));
  int*   cursor  = (int*)  (ws + 2 * BUF + (1 << 19) + 4096 + 2 * (1 << 19));
  int*   scol    = (int*)  (ws + 2 * BUF + (1 << 19) + 4096 + 3 * (1 << 19));
  float* sval    = (float*)(ws + 2 * BUF + (1 << 19) + 4096 + 3 * (1 << 19) +
                            (size_t)N_NNZ * 4);

  // ---- build CSR (once; reused by all 3 layers) ----
  hipMemsetAsync(cnt, 0, (size_t)N_NODES * sizeof(int), stream);
  hist_kernel<<<(N_NNZ + 255) / 256, 256, 0, stream>>>(adj_row, cnt, N_NNZ);
  scan_kernel<<<1, 1024, 0, stream>>>(cnt, row_ptr, cursor, N_NODES, N_NNZ);
  scatter_kernel<<<(N_NNZ + 255) / 256, 256, 0, stream>>>(
      adj_row, adj_col, adj_val, cursor, scol, sval, N_NNZ);

  auto run_layer = [&](const float* xin, int K, const float* W, const float* b,
                       int F) {
    int Kp = ((K + 31) / 32) * 32;
    wcast_kernel<<<(F * Kp + 255) / 256, 256, 0, stream>>>(W, Wt, K, Kp, F);
    if (F == 128) {
      mfma_gemm<64, 128, 2, 2><<<(N_NODES + 63) / 64, 256, 0, stream>>>(
          xin, Wt, sup, N_NODES, K, Kp, F);
      spmm_csr128_kernel<<<(N_NODES * 64 + 255) / 256, 256, 0, stream>>>(
          row_ptr, scol, sval, sup, b, xbuf, N_NODES);
    } else {
      mfma_gemm<64, 64, 4, 1><<<(N_NODES + 63) / 64, 256, 0, stream>>>(
          xin, Wt, sup, N_NODES, K, Kp, F);
      spmm_csr64_kernel<<<(N_NODES * 64 + 255) / 256, 256, 0, stream>>>(
          row_ptr, scol, sval, sup, b, xbuf, N_NODES);
    }
    hipMemsetAsync(csum, 0, F * sizeof(float), stream);
    colsum_kernel<<<(N_NODES + 127) / 128, F, 0, stream>>>(
        xbuf, csum, N_NODES, F, 128);
    pairnorm_kernel<<<(N_NODES * 64 + 255) / 256, 256, 0, stream>>>(
        xbuf, csum, N_NODES, F);
  };

  run_layer(in_feature, F_IN, W0, b0, F_HID);
  run_layer(xbuf,       F_HID, W1, b1, F_HID);
  run_layer(xbuf,       F_HID, W2, b2, F_OUT);

  decode_kernel<<<((N_POS + N_NEG) * 64 + 255) / 256, 256, 0, stream>>>(
      pos_ei, neg_ei, xbuf, out, N_POS, N_POS + N_NEG, F_OUT);
}